// Round 17
// baseline (525.715 us; speedup 1.0000x reference)
//
#include <hip/hip_runtime.h>

typedef _Float16 f16;
typedef f16  f16x8 __attribute__((ext_vector_type(8)));
typedef float f32x4 __attribute__((ext_vector_type(4)));

#define S3 3145728LL   // per-batch per-component elems (12*256*16*64 = 4096*768)

__device__ __forceinline__ f32x4 mm(f16x8 a, f16x8 b, f32x4 c) {
  return __builtin_amdgcn_mfma_f32_16x16x32_f16(a, b, c, 0, 0, 0);
}
__device__ __forceinline__ void BAR() { asm volatile("s_barrier" ::: "memory"); }

// epilogue LDS swizzle for [128][128] f16 tile
__device__ __forceinline__ int esw(int t, int col) {
  return t * 128 + ((((col >> 3) ^ ((t ^ (t >> 3)) & 7)) << 3) | (col & 7));
}
// swizzle for [256][64] f16 tile (attn_spat O staging)
__device__ __forceinline__ int oesw(int t, int col) {
  return t * 64 + ((((col >> 3) ^ (t & 7)) << 3) | (col & 7));
}

// ---------------- transpose + fp32->fp16 convert: out[Cc][R] = in[R][Cc] ----
__global__ void cvt_T_kernel(const float* __restrict__ in, f16* __restrict__ out,
                             int R, int Cc) {
  __shared__ float tile[32][33];
  int tc = blockIdx.x, tr = blockIdx.y;
  int lr = threadIdx.x & 31, lw = threadIdx.x >> 5;
  int c0 = tc * 32, r0 = tr * 32;
#pragma unroll
  for (int i = 0; i < 4; i++)
    tile[lw + 8 * i][lr] = in[(size_t)(r0 + lw + 8 * i) * Cc + c0 + lr];
  __syncthreads();
#pragma unroll
  for (int i = 0; i < 4; i++)
    out[(size_t)(c0 + lw + 8 * i) * R + r0 + lr] = (f16)tile[lr][lw + 8 * i];
}

// ---------------- x fp32 -> f16 (NT reads: x is never re-read) -------------
__global__ void cvt_x_kernel(const float* __restrict__ in, f16* __restrict__ out) {
  size_t i = ((size_t)blockIdx.x * 256 + threadIdx.x) * 8;
  f32x4 a = __builtin_nontemporal_load((const f32x4*)(in + i));
  f32x4 b = __builtin_nontemporal_load((const f32x4*)(in + i + 4));
  f16x8 o;
#pragma unroll
  for (int j = 0; j < 4; j++) { o[j] = (f16)a[j]; o[4 + j] = (f16)b[j]; }
  *(f16x8*)(out + i) = o;
}

// ====== GEMM core: 128x128 tile, BK=32, 32KB LDS, 4 blocks/CU ==============
// LDS per dbuf: A 8KB [128 rows][32 cols] + B 8KB. Granule swizzle:
// slot g of row r holds k-chunk (g ^ (r&3)); reads are bank-minimal
// (even rows -> banks 0-15, odd -> 16-31, 8 dwords/bank).
// Staging: 4 gload_lds/thread/tile; vmcnt(4) => tile t+1 resident.
#define Q3_A(c, kt) do { \
    __builtin_amdgcn_global_load_lds( \
      (const __attribute__((address_space(1))) void*)(aSrc + (size_t)(kt) * 32), \
      (__attribute__((address_space(3))) void*)((char*)lds + (c) * 16384 + (tid >> 2) * 64 + (tid & 3) * 16), 16, 0, 0); \
    __builtin_amdgcn_global_load_lds( \
      (const __attribute__((address_space(1))) void*)(aSrc + 49152 + (size_t)(kt) * 32), \
      (__attribute__((address_space(3))) void*)((char*)lds + (c) * 16384 + 4096 + (tid >> 2) * 64 + (tid & 3) * 16), 16, 0, 0); \
  } while (0)
#define Q3_B(c, kt) do { \
    __builtin_amdgcn_global_load_lds( \
      (const __attribute__((address_space(1))) void*)(bSrc + (size_t)(kt) * 32), \
      (__attribute__((address_space(3))) void*)((char*)lds + (c) * 16384 + 8192 + (tid >> 2) * 64 + (tid & 3) * 16), 16, 0, 0); \
    __builtin_amdgcn_global_load_lds( \
      (const __attribute__((address_space(1))) void*)(bSrc + 49152 + (size_t)(kt) * 32), \
      (__attribute__((address_space(3))) void*)((char*)lds + (c) * 16384 + 12288 + (tid >> 2) * 64 + (tid & 3) * 16), 16, 0, 0); \
  } while (0)

#define GEMM32_LOOP()                                                          \
  f16x8 af[4], bf[4];                                                          \
  _Pragma("unroll 2")                                                          \
  for (int t = 0; t < 24; ++t) {                                               \
    int c = t & 1;                                                             \
    const char* ab = (const char*)lds + c * 16384;                             \
    const char* bb = ab + 8192;                                                \
    int rA = wr * 64 + l16;                                                    \
    int rB = wc * 64 + l16;                                                    \
    _Pragma("unroll")                                                          \
    for (int mf = 0; mf < 4; mf++)                                             \
      af[mf] = *(const f16x8*)(ab + (rA + mf * 16) * 64 + cb);                 \
    _Pragma("unroll")                                                          \
    for (int nf = 0; nf < 4; nf++)                                             \
      bf[nf] = *(const f16x8*)(bb + (rB + nf * 16) * 64 + cb);                 \
    asm volatile("s_waitcnt lgkmcnt(0)" ::: "memory");                         \
    BAR();                                                                     \
    if (t < 22) { Q3_A(c, t + 2); Q3_B(c, t + 2); }                            \
    __builtin_amdgcn_s_setprio(1);                                             \
    _Pragma("unroll")                                                          \
    for (int mf = 0; mf < 4; mf++)                                             \
      _Pragma("unroll")                                                        \
      for (int nf = 0; nf < 4; nf++)                                           \
        acc[mf][nf] = mm(af[mf], bf[nf], acc[mf][nf]);                         \
    __builtin_amdgcn_s_setprio(0);                                             \
    if (t < 22) asm volatile("s_waitcnt vmcnt(4)" ::: "memory");               \
    else        asm volatile("s_waitcnt vmcnt(0)" ::: "memory");               \
    BAR();                                                                     \
  }

#define GEMM32_PROLOGUE()                                                      \
  Q3_A(0, 0); Q3_B(0, 0); Q3_A(1, 1); Q3_B(1, 1);                              \
  asm volatile("s_waitcnt vmcnt(4)" ::: "memory");                             \
  BAR();

__global__ __launch_bounds__(256, 4) void gemm_qkvT(
    const f16* __restrict__ A, const f16* __restrict__ Bt,
    f16* __restrict__ area, long long cstr_) {
  __shared__ f16 lds[16384];   // 32KB: K-loop 2x(A 8KB|B 8KB); epilogue C-tile
  size_t cstr = (size_t)cstr_;
  int id  = blockIdx.x;
  int cpx = gridDim.x >> 3;
  int id2 = (id & 7) * cpx + (id >> 3);       // XCD swizzle (grid % 8 == 0)
  int sr = id2 / 288, rr = id2 % 288;
  int bm = sr * 8 + (rr & 7), bn = rr >> 3;   // bm 0..G*32-1, bn 0..35

  int tid = threadIdx.x;
  int wave = tid >> 6, lane = tid & 63;
  int l16 = lane & 15, lq = lane >> 4;
  int wr = wave >> 1, wc = wave & 1;          // 2 x 2 wave grid
  int cb = ((lq ^ (l16 & 3)) << 4);           // read-side granule swizzle

  const f16* aSrc = A  + (size_t)(bm * 128 + (tid >> 2)) * 768 +
                    (((tid & 3) ^ ((tid >> 2) & 3)) << 3);
  const f16* bSrc = Bt + (size_t)(bn * 128 + (tid >> 2)) * 768 +
                    (((tid & 3) ^ ((tid >> 2) & 3)) << 3);

  f32x4 zz = {0.f, 0.f, 0.f, 0.f};
  f32x4 acc[4][4];
#pragma unroll
  for (int m = 0; m < 4; m++)
#pragma unroll
    for (int n = 0; n < 4; n++) acc[m][n] = zz;

  GEMM32_PROLOGUE();
  GEMM32_LOOP();

  // ---- coalesced LDS epilogue (32KB [128][128] C-tile) ----
  int s  = bn / 6;
  int h0 = (bn % 6) * 2;
  size_t comp;
  if (s == 0) comp = 0; else if (s == 1) comp = 1; else if (s == 2) comp = 3;
  else if (s == 3) comp = 4; else if (s == 4) comp = 2; else comp = 5;
  int g = (bm * 128) >> 12;
  size_t base = comp * cstr + (size_t)g * S3;
  int n0 = (bm & 31) * 8;

  __syncthreads();
#pragma unroll
  for (int mi = 0; mi < 4; mi++)
#pragma unroll
    for (int ni = 0; ni < 4; ni++)
#pragma unroll
      for (int r = 0; r < 4; r++) {
        int t = wr * 64 + mi * 16 + lq * 4 + r;
        int col = wc * 64 + ni * 16 + l16;
        lds[esw(t, col)] = (f16)acc[mi][ni][r];
      }
  __syncthreads();

  if (s < 2) {            // qc/kc [h][n][c][d]
#pragma unroll
    for (int i = 0; i < 4; i++) {
      int u = wave * 4 + i;
      int hl = u >> 3, j16 = u & 7;
#pragma unroll
      for (int half = 0; half < 2; half++) {
        int e0 = half * 512 + lane * 8;
        int cc = e0 >> 6, d0 = e0 & 63;
        f16x8 v = *(const f16x8*)&lds[esw(j16 * 16 + cc, hl * 64 + d0)];
        __builtin_nontemporal_store(v, (f16x8*)&area[base +
            (size_t)(h0 + hl) * 262144 + (size_t)(n0 + j16) * 1024 + e0]);
      }
    }
  } else if (s < 4) {     // qs/ks [h][c][n][d]
#pragma unroll
    for (int i = 0; i < 8; i++) {
      int u = wave * 8 + i;
      int hl = u >> 4, cc = u & 15;
      int e = lane * 8;
      int nl = e >> 6, d0 = e & 63;
      f16x8 v = *(const f16x8*)&lds[esw(nl * 16 + cc, hl * 64 + d0)];
      __builtin_nontemporal_store(v, (f16x8*)&area[base +
          (size_t)((h0 + hl) * 16 + cc) * 16384 + (size_t)n0 * 64 + e]);
    }
  } else if (s == 4) {    // vc [h][n][d][c]
#pragma unroll
    for (int i = 0; i < 4; i++) {
      int u = wave * 4 + i;
      int hl = u >> 3, j8 = u & 7;
#pragma unroll
      for (int half = 0; half < 2; half++) {
        int e0 = half * 512 + lane * 8;
        int d0 = e0 >> 4, cb2 = e0 & 15;
        f16x8 v;
#pragma unroll
        for (int j = 0; j < 8; j++)
          v[j] = lds[esw(j8 * 16 + cb2 + j, hl * 64 + d0)];
        __builtin_nontemporal_store(v, (f16x8*)&area[base +
            (size_t)((h0 + hl) * 256 + n0 + j8) * 1024 + e0]);
      }
    }
  } else {                // vs blocked [h][c][nb8][d][nl8]
#pragma unroll
    for (int i = 0; i < 8; i++) {
      int u = wave * 8 + i;
      int hl = u >> 4, cc = u & 15;
      int e = lane * 8;
      int d0 = e >> 3;
      f16x8 v;
#pragma unroll
      for (int j = 0; j < 8; j++)
        v[j] = lds[esw(j * 16 + cc, hl * 64 + d0)];
      __builtin_nontemporal_store(v, (f16x8*)&area[base +
          ((size_t)((h0 + hl) * 16 + cc) * 32 + (bm & 31)) * 512 + e]);
    }
  }
}

// ---------- proj GEMM: 128x128 tile, BK=32, out = A*wpt^T + bias ------------
__global__ __launch_bounds__(256, 4) void gemm_projT(
    const f16* __restrict__ A,       // prod [G*4096][768] (comp6)
    const f16* __restrict__ Bt,      // wpt [768][768]
    const float* __restrict__ bias, float* __restrict__ Cout) {
  __shared__ f16 lds[16384];
  int id  = blockIdx.x;
  int cpx = gridDim.x >> 3;
  int id2 = (id & 7) * cpx + (id >> 3);       // grid = G*192, %8==0
  int sr = id2 / 48, rr = id2 % 48;
  int bm = sr * 8 + (rr & 7), bn = rr >> 3;   // bm 0..G*32-1, bn 0..5

  int tid = threadIdx.x;
  int wave = tid >> 6, lane = tid & 63;
  int l16 = lane & 15, lq = lane >> 4;
  int wr = wave >> 1, wc = wave & 1;
  int cb = ((lq ^ (l16 & 3)) << 4);

  const f16* aSrc = A  + (size_t)(bm * 128 + (tid >> 2)) * 768 +
                    (((tid & 3) ^ ((tid >> 2) & 3)) << 3);
  const f16* bSrc = Bt + (size_t)(bn * 128 + (tid >> 2)) * 768 +
                    (((tid & 3) ^ ((tid >> 2) & 3)) << 3);

  f32x4 zz = {0.f, 0.f, 0.f, 0.f};
  f32x4 acc[4][4];
#pragma unroll
  for (int m = 0; m < 4; m++)
#pragma unroll
    for (int n = 0; n < 4; n++) acc[m][n] = zz;

  GEMM32_PROLOGUE();
  GEMM32_LOOP();

  // direct fp32 epilogue with bias
#pragma unroll
  for (int ni = 0; ni < 4; ni++) {
    int col = bn * 128 + wc * 64 + ni * 16 + l16;
    float bb = bias[col];
#pragma unroll
    for (int mi = 0; mi < 4; mi++) {
#pragma unroll
      for (int r = 0; r < 4; r++) {
        int row = bm * 128 + wr * 64 + mi * 16 + lq * 4 + r;
        __builtin_nontemporal_store(acc[mi][ni][r] + bb,
                                    &Cout[(size_t)row * 768 + col]);
      }
    }
  }
}

// ---------------- channel attention: per (g,n); xc OUT = [n][h][c][d] -------
__global__ __launch_bounds__(256) void attn_chan_kernel(f16* __restrict__ area,
                                                        long long cstr_) {
  size_t cstr = (size_t)cstr_;
  int blk = blockIdx.x;
  int g = blk >> 8, n = blk & 255;
  size_t goff = (size_t)g * S3;
  int tid = threadIdx.x;
  int wave = tid >> 6, lane = tid & 63;
  int l16 = lane & 15, lq = lane >> 4;
  __shared__ f16 prl[12288];
  __shared__ f16 plds[4][16][40];

  if (lane < 16) {
#pragma unroll
    for (int j = 0; j < 16; j++) plds[wave][lane][16 + j] = (f16)0.f;  // zero K-pad
  }
  __syncthreads();

  f32x4 zz = {0.f, 0.f, 0.f, 0.f};
  for (int hi = 0; hi < 3; hi++) {
    int h = wave + hi * 4;
    const f16* q = area + 0 * cstr + goff + (size_t)((h * 256 + n) * 16) * 64;
    const f16* k = area + 1 * cstr + goff + (size_t)((h * 256 + n) * 16) * 64;
    const f16* v = area + 2 * cstr + goff + (size_t)((h * 256 + n) * 64) * 16; // [d][c]
    f16x8 a0 = *(const f16x8*)&q[l16 * 64 + lq * 8];
    f16x8 a1 = *(const f16x8*)&q[l16 * 64 + 32 + lq * 8];
    f16x8 b0 = *(const f16x8*)&k[l16 * 64 + lq * 8];
    f16x8 b1 = *(const f16x8*)&k[l16 * 64 + 32 + lq * 8];
    f32x4 s = mm(a1, b1, mm(a0, b0, zz));
    float p[4];
#pragma unroll
    for (int r = 0; r < 4; r++) {
      float t = s[r] * 0.125f;
      float mx = t;
      mx = fmaxf(mx, __shfl_xor(mx, 1));
      mx = fmaxf(mx, __shfl_xor(mx, 2));
      mx = fmaxf(mx, __shfl_xor(mx, 4));
      mx = fmaxf(mx, __shfl_xor(mx, 8));
      float e = __expf(t - mx);
      float sum = e;
      sum += __shfl_xor(sum, 1);
      sum += __shfl_xor(sum, 2);
      sum += __shfl_xor(sum, 4);
      sum += __shfl_xor(sum, 8);
      p[r] = e / sum;
    }
#pragma unroll
    for (int r = 0; r < 4; r++)
      plds[wave][lq * 4 + r][l16] = (f16)p[r];
    f16x8 ap = *(const f16x8*)&plds[wave][l16][lq * 8]; // k>=16 are zeros
#pragma unroll
    for (int nt = 0; nt < 4; nt++) {
      f16x8 bv = *(const f16x8*)&v[(nt * 16 + l16) * 16 + lq * 8];
      f32x4 o = mm(ap, bv, zz);
#pragma unroll
      for (int r = 0; r < 4; r++) {
        int cq = lq * 4 + r, d = nt * 16 + l16;
        prl[h * 1024 + cq * 64 + d] = (f16)o[r];
      }
    }
  }
  __syncthreads();
  f16* xc = area + 6 * cstr + goff + (size_t)n * 12288;
#pragma unroll
  for (int i = 0; i < 6; i++) {
    f16x8 v = *(const f16x8*)&prl[i * 2048 + tid * 8];
    __builtin_nontemporal_store(v, (f16x8*)&xc[i * 2048 + tid * 8]);
  }
}

// ---------------- spatial attention + combine: per (g,h,c) ------------------
// Epilogue: prod = O * xc written IN-PLACE over xc (comp6, [n][h][c][d]).
__global__ __launch_bounds__(512) void attn_spat_kernel(f16* __restrict__ area,
                                                        long long cstr_) {
  size_t cstr = (size_t)cstr_;
  int blk = blockIdx.x;
  int g = blk / 192, rem = blk % 192;
  int h = rem >> 4, c = rem & 15;
  size_t goff = (size_t)g * S3;
  const f16* qs = area + 3 * cstr + goff + (size_t)((h * 16 + c) * 256) * 64;
  const f16* ks = area + 4 * cstr + goff + (size_t)((h * 16 + c) * 256) * 64;
  const f16* vsb = area + 5 * cstr + goff + (size_t)(h * 16 + c) * 16384; // [nb8][d][nl8]
  f16* xcn = area + 6 * cstr + goff;   // xc in / prod out, [n][h][c][d]

  int tid = threadIdx.x;
  int wave = tid >> 6, lane = tid & 63;
  int l16 = lane & 15, lq = lane >> 4;
  __shared__ f16 plds[8][32][40];
  __shared__ f16 osm[16384];          // [256][64] swizzled (oesw)

  f32x4 zz = {0.f, 0.f, 0.f, 0.f};
  f16x8 aq[2][2];
#pragma unroll
  for (int m = 0; m < 2; m++)
#pragma unroll
    for (int kd = 0; kd < 2; kd++)
      aq[m][kd] = *(const f16x8*)&qs[(size_t)(wave * 32 + m * 16 + l16) * 64 + kd * 32 + lq * 8];

  f32x4 o[2][4];
  float mrow[2][4], lrow[2][4];
#pragma unroll
  for (int m = 0; m < 2; m++) {
#pragma unroll
    for (int n = 0; n < 4; n++) o[m][n] = zz;
#pragma unroll
    for (int r = 0; r < 4; r++) { mrow[m][r] = -1e30f; lrow[m][r] = 0.f; }
  }

  for (int kc = 0; kc < 8; kc++) {
    int k0 = kc * 32;
    f16x8 bk00 = *(const f16x8*)&ks[(size_t)(k0 + l16) * 64 + lq * 8];
    f16x8 bk01 = *(const f16x8*)&ks[(size_t)(k0 + l16) * 64 + 32 + lq * 8];
    f16x8 bk10 = *(const f16x8*)&ks[(size_t)(k0 + 16 + l16) * 64 + lq * 8];
    f16x8 bk11 = *(const f16x8*)&ks[(size_t)(k0 + 16 + l16) * 64 + 32 + lq * 8];
    f32x4 st[2][2];
#pragma unroll
    for (int m = 0; m < 2; m++) {
      st[m][0] = mm(aq[m][1], bk01, mm(aq[m][0], bk00, zz));
      st[m][1] = mm(aq[m][1], bk11, mm(aq[m][0], bk10, zz));
    }
#pragma unroll
    for (int m = 0; m < 2; m++) {
#pragma unroll
      for (int r = 0; r < 4; r++) {
        float s0 = st[m][0][r] * 0.125f, s1 = st[m][1][r] * 0.125f;
        float t = fmaxf(s0, s1);
        t = fmaxf(t, __shfl_xor(t, 1));
        t = fmaxf(t, __shfl_xor(t, 2));
        t = fmaxf(t, __shfl_xor(t, 4));
        t = fmaxf(t, __shfl_xor(t, 8));
        float mold = mrow[m][r];
        if (!__all(t - mold <= 8.f)) {   // defer-max
          float mnew = fmaxf(mold, t);
          float fac  = __expf(mold - mnew);
          mrow[m][r] = mnew;
          lrow[m][r] *= fac;
          o[m][0][r] *= fac; o[m][1][r] *= fac; o[m][2][r] *= fac; o[m][3][r] *= fac;
          mold = mnew;
        }
        float p0 = __expf(s0 - mold), p1 = __expf(s1 - mold);
        lrow[m][r] += p0 + p1;
        int prow = m * 16 + lq * 4 + r;
        plds[wave][prow][l16]      = (f16)p0;
        plds[wave][prow][16 + l16] = (f16)p1;
      }
    }
    f16x8 ap0 = *(const f16x8*)&plds[wave][l16][lq * 8];
    f16x8 ap1 = *(const f16x8*)&plds[wave][16 + l16][lq * 8];
#pragma unroll
    for (int n = 0; n < 4; n++) {
      f16x8 bv = *(const f16x8*)&vsb[((k0 >> 3) + lq) * 512 + (n * 16 + l16) * 8];
      o[0][n] = mm(ap0, bv, o[0][n]);
      o[1][n] = mm(ap1, bv, o[1][n]);
    }
  }
#pragma unroll
  for (int m = 0; m < 2; m++)
#pragma unroll
    for (int r = 0; r < 4; r++) {
      float l = lrow[m][r];
      l += __shfl_xor(l, 1);
      l += __shfl_xor(l, 2);
      l += __shfl_xor(l, 4);
      l += __shfl_xor(l, 8);
      lrow[m][r] = 1.0f / l;
    }
#pragma unroll
  for (int m = 0; m < 2; m++)
#pragma unroll
    for (int n = 0; n < 4; n++)
#pragma unroll
      for (int r = 0; r < 4; r++) {
        int row = wave * 32 + m * 16 + lq * 4 + r;
        osm[oesw(row, n * 16 + l16)] = (f16)(o[m][n][r] * lrow[m][r]);
      }
  __syncthreads();
  size_t hc64 = (size_t)(h * 16 + c) * 64;
#pragma unroll
  for (int i = 0; i < 4; i++) {
    int row = i * 64 + (tid >> 3);
    int dp  = (tid & 7) * 8;
    size_t dst = (size_t)row * 12288 + hc64 + dp;
    f16x8 v   = *(const f16x8*)&osm[oesw(row, dp)];
    f16x8 xcv = *(const f16x8*)&xcn[dst];
    f16x8 pv;
#pragma unroll
    for (int j = 0; j < 8; j++)
      pv[j] = (f16)((float)v[j] * (float)xcv[j]);
    __builtin_nontemporal_store(pv, (f16x8*)&xcn[dst]);
  }
}

// ---------------- host ------------------------------------------------------
extern "C" void kernel_launch(void* const* d_in, const int* in_sizes, int n_in,
                              void* d_out, int out_size, void* d_ws, size_t ws_size,
                              hipStream_t stream) {
  const float* x      = (const float*)d_in[0];
  const float* w_qkv  = (const float*)d_in[1];
  const float* w_proj = (const float*)d_in[2];
  const float* b_proj = (const float*)d_in[3];
  float* out = (float*)d_out;
  f16* ws = (f16*)d_ws;

  const size_t W16T = 4608ull * 768;
  const size_t WPT  = 768ull * 768;
  f16* w16t = ws;
  f16* wpt  = ws + W16T;
  f16* area = wpt + WPT;

  // 7-component plan: 0 qc, 1 kc, 2 vc, 3 qs, 4 ks, 5 vs, 6 x16->xc->prod
  int G = 8;  // batches per chunk; shrink until scratch fits
  while (G > 1 && (W16T + WPT + 7ull * G * S3) * 2 > ws_size) G >>= 1;
  int nch = 8 / G;
  long long cstr = (long long)G * S3;
  f16* x16 = area + 6 * (size_t)cstr;

  cvt_T_kernel<<<dim3(144, 24), 256, 0, stream>>>(w_qkv, w16t, 768, 4608);
  cvt_T_kernel<<<dim3(24, 24), 256, 0, stream>>>(w_proj, wpt, 768, 768);

  for (int ch = 0; ch < nch; ch++) {
    size_t b0 = (size_t)ch * G;
    cvt_x_kernel<<<G * 1536, 256, 0, stream>>>(x + b0 * S3, x16);
    gemm_qkvT<<<G * 1152, 256, 0, stream>>>(x16, w16t, area, cstr);
    attn_chan_kernel<<<G * 256, 256, 0, stream>>>(area, cstr);   // xc -> comp6
    attn_spat_kernel<<<G * 192, 512, 0, stream>>>(area, cstr);   // prod in-place
    gemm_projT<<<G * 192, 256, 0, stream>>>(area + 6 * (size_t)cstr, wpt, b_proj,
                                            out + b0 * S3);
  }
}

// Round 18
// 486.230 us; speedup vs baseline: 1.0812x; 1.0812x over previous
//
#include <hip/hip_runtime.h>

typedef _Float16 f16;
typedef f16  f16x8 __attribute__((ext_vector_type(8)));
typedef float f32x4 __attribute__((ext_vector_type(4)));

#define S3 3145728LL   // per-batch per-component elems (12*256*16*64 = 4096*768)

__device__ __forceinline__ f32x4 mm(f16x8 a, f16x8 b, f32x4 c) {
  return __builtin_amdgcn_mfma_f32_16x16x32_f16(a, b, c, 0, 0, 0);
}
__device__ __forceinline__ void BAR() { asm volatile("s_barrier" ::: "memory"); }

// epilogue LDS swizzle for [128][128] f16 tile
__device__ __forceinline__ int esw(int t, int col) {
  return t * 128 + ((((col >> 3) ^ ((t ^ (t >> 3)) & 7)) << 3) | (col & 7));
}
// swizzle for [256][64] f16 tile (attn_spat O staging)
__device__ __forceinline__ int oesw(int t, int col) {
  return t * 64 + ((((col >> 3) ^ (t & 7)) << 3) | (col & 7));
}

// ---------------- transpose + fp32->fp16 convert: out[Cc][R] = in[R][Cc] ----
__global__ void cvt_T_kernel(const float* __restrict__ in, f16* __restrict__ out,
                             int R, int Cc) {
  __shared__ float tile[32][33];
  int tc = blockIdx.x, tr = blockIdx.y;
  int lr = threadIdx.x & 31, lw = threadIdx.x >> 5;
  int c0 = tc * 32, r0 = tr * 32;
#pragma unroll
  for (int i = 0; i < 4; i++)
    tile[lw + 8 * i][lr] = in[(size_t)(r0 + lw + 8 * i) * Cc + c0 + lr];
  __syncthreads();
#pragma unroll
  for (int i = 0; i < 4; i++)
    out[(size_t)(c0 + lw + 8 * i) * R + r0 + lr] = (f16)tile[lr][lw + 8 * i];
}

// ---------------- x fp32 -> f16 (NT reads: x is never re-read) -------------
__global__ void cvt_x_kernel(const float* __restrict__ in, f16* __restrict__ out) {
  size_t i = ((size_t)blockIdx.x * 256 + threadIdx.x) * 8;
  f32x4 a = __builtin_nontemporal_load((const f32x4*)(in + i));
  f32x4 b = __builtin_nontemporal_load((const f32x4*)(in + i + 4));
  f16x8 o;
#pragma unroll
  for (int j = 0; j < 4; j++) { o[j] = (f16)a[j]; o[4 + j] = (f16)b[j]; }
  *(f16x8*)(out + i) = o;
}

// =================== QKV GEMM: 128x128 tile, BK=64, 64KB LDS ================
#define QST_A(c, q, kt) __builtin_amdgcn_global_load_lds( \
    (const __attribute__((address_space(1))) void*)(aSrc + (size_t)(q) * 24576 + (size_t)(kt) * 64), \
    (__attribute__((address_space(3))) void*)((char*)lds + (c) * 32768 + (q) * 1024 * 4 + wave * 1024), 16, 0, 0)
#define QST_B(c, q, kt) __builtin_amdgcn_global_load_lds( \
    (const __attribute__((address_space(1))) void*)(bSrc + (size_t)(q) * 24576 + (size_t)(kt) * 64), \
    (__attribute__((address_space(3))) void*)((char*)lds + 16384 + (c) * 32768 + (q) * 1024 * 4 + wave * 1024), 16, 0, 0)

__global__ __launch_bounds__(256, 2) void gemm_qkvT(
    const f16* __restrict__ A, const f16* __restrict__ Bt,
    f16* __restrict__ area, long long cstr_) {
  __shared__ f16 lds[32768];   // 64KB: 2 x (A 16KB | B 16KB); epilogue reuses 32KB
  size_t cstr = (size_t)cstr_;
  int id  = blockIdx.x;
  int cpx = gridDim.x >> 3;
  int id2 = (id & 7) * cpx + (id >> 3);       // XCD swizzle (grid % 8 == 0)
  int sr = id2 / 288, rr = id2 % 288;
  int bm = sr * 8 + (rr & 7), bn = rr >> 3;   // bm 0..G*32-1, bn 0..35

  int tid = threadIdx.x;
  int wave = tid >> 6, lane = tid & 63;
  int l16 = lane & 15, lq = lane >> 4;
  int wr = wave >> 1, wc = wave & 1;          // 2 x 2 wave grid
  int l7 = l16 & 7;
  int cb0 = ((lq) ^ l7) << 4;
  int cb1 = ((4 + lq) ^ l7) << 4;

  const f16* aSrc = A  + (size_t)(bm * 128 + (tid >> 3)) * 768 +
                    (((tid & 7) ^ ((tid >> 3) & 7)) << 3);
  const f16* bSrc = Bt + (size_t)(bn * 128 + (tid >> 3)) * 768 +
                    (((tid & 7) ^ ((tid >> 3) & 7)) << 3);

  f32x4 zz = {0.f, 0.f, 0.f, 0.f};
  f32x4 acc[4][4];
#pragma unroll
  for (int m = 0; m < 4; m++)
#pragma unroll
    for (int n = 0; n < 4; n++) acc[m][n] = zz;

#pragma unroll
  for (int q = 0; q < 4; q++) { QST_A(0, q, 0); }
#pragma unroll
  for (int q = 0; q < 4; q++) { QST_B(0, q, 0); }
#pragma unroll
  for (int q = 0; q < 4; q++) { QST_A(1, q, 1); }
#pragma unroll
  for (int q = 0; q < 4; q++) { QST_B(1, q, 1); }
  asm volatile("s_waitcnt vmcnt(8)" ::: "memory");
  BAR();

  f16x8 af[4][2], bf[4][2];
#pragma unroll 2
  for (int t = 0; t < 12; ++t) {
    int c = t & 1;
    const char* ab = (const char*)lds + c * 32768;
    const char* bb = ab + 16384;
    int rA = wr * 64 + l16;
    int rB = wc * 64 + l16;
#pragma unroll
    for (int mf = 0; mf < 4; mf++) {
      af[mf][0] = *(const f16x8*)(ab + (rA + mf * 16) * 128 + cb0);
      af[mf][1] = *(const f16x8*)(ab + (rA + mf * 16) * 128 + cb1);
    }
#pragma unroll
    for (int nf = 0; nf < 4; nf++) {
      bf[nf][0] = *(const f16x8*)(bb + (rB + nf * 16) * 128 + cb0);
      bf[nf][1] = *(const f16x8*)(bb + (rB + nf * 16) * 128 + cb1);
    }
    asm volatile("s_waitcnt lgkmcnt(0)" ::: "memory");
    BAR();
    if (t < 10) {
#pragma unroll
      for (int q = 0; q < 4; q++) { QST_A(c, q, t + 2); }
#pragma unroll
      for (int q = 0; q < 4; q++) { QST_B(c, q, t + 2); }
    }
    __builtin_amdgcn_s_setprio(1);
#pragma unroll
    for (int ks = 0; ks < 2; ks++)
#pragma unroll
      for (int mf = 0; mf < 4; mf++)
#pragma unroll
        for (int nf = 0; nf < 4; nf++)
          acc[mf][nf] = mm(af[mf][ks], bf[nf][ks], acc[mf][nf]);
    __builtin_amdgcn_s_setprio(0);
    if (t < 10) asm volatile("s_waitcnt vmcnt(8)" ::: "memory");
    else        asm volatile("s_waitcnt vmcnt(0)" ::: "memory");
    BAR();
  }

  // ---- coalesced LDS epilogue (32KB [128][128] C-tile) ----
  int s  = bn / 6;
  int h0 = (bn % 6) * 2;
  size_t comp;
  if (s == 0) comp = 0; else if (s == 1) comp = 1; else if (s == 2) comp = 3;
  else if (s == 3) comp = 4; else if (s == 4) comp = 2; else comp = 5;
  int g = (bm * 128) >> 12;
  size_t base = comp * cstr + (size_t)g * S3;
  int n0 = (bm & 31) * 8;

  __syncthreads();
#pragma unroll
  for (int mi = 0; mi < 4; mi++)
#pragma unroll
    for (int ni = 0; ni < 4; ni++)
#pragma unroll
      for (int r = 0; r < 4; r++) {
        int t = wr * 64 + mi * 16 + lq * 4 + r;
        int col = wc * 64 + ni * 16 + l16;
        lds[esw(t, col)] = (f16)acc[mi][ni][r];
      }
  __syncthreads();

  if (s < 2) {            // qc/kc [h][n][c][d]
#pragma unroll
    for (int i = 0; i < 4; i++) {
      int u = wave * 4 + i;
      int hl = u >> 3, j16 = u & 7;
#pragma unroll
      for (int half = 0; half < 2; half++) {
        int e0 = half * 512 + lane * 8;
        int cc = e0 >> 6, d0 = e0 & 63;
        f16x8 v = *(const f16x8*)&lds[esw(j16 * 16 + cc, hl * 64 + d0)];
        __builtin_nontemporal_store(v, (f16x8*)&area[base +
            (size_t)(h0 + hl) * 262144 + (size_t)(n0 + j16) * 1024 + e0]);
      }
    }
  } else if (s < 4) {     // qs/ks [h][c][n][d]
#pragma unroll
    for (int i = 0; i < 8; i++) {
      int u = wave * 8 + i;
      int hl = u >> 4, cc = u & 15;
      int e = lane * 8;
      int nl = e >> 6, d0 = e & 63;
      f16x8 v = *(const f16x8*)&lds[esw(nl * 16 + cc, hl * 64 + d0)];
      __builtin_nontemporal_store(v, (f16x8*)&area[base +
          (size_t)((h0 + hl) * 16 + cc) * 16384 + (size_t)n0 * 64 + e]);
    }
  } else if (s == 4) {    // vc [h][n][d][c]
#pragma unroll
    for (int i = 0; i < 4; i++) {
      int u = wave * 4 + i;
      int hl = u >> 3, j8 = u & 7;
#pragma unroll
      for (int half = 0; half < 2; half++) {
        int e0 = half * 512 + lane * 8;
        int d0 = e0 >> 4, cb = e0 & 15;
        f16x8 v;
#pragma unroll
        for (int j = 0; j < 8; j++)
          v[j] = lds[esw(j8 * 16 + cb + j, hl * 64 + d0)];
        __builtin_nontemporal_store(v, (f16x8*)&area[base +
            (size_t)((h0 + hl) * 256 + n0 + j8) * 1024 + e0]);
      }
    }
  } else {                // vs blocked [h][c][nb8][d][nl8]
#pragma unroll
    for (int i = 0; i < 8; i++) {
      int u = wave * 8 + i;
      int hl = u >> 4, cc = u & 15;
      int e = lane * 8;
      int d0 = e >> 3;
      f16x8 v;
#pragma unroll
      for (int j = 0; j < 8; j++)
        v[j] = lds[esw(j * 16 + cc, hl * 64 + d0)];
      __builtin_nontemporal_store(v, (f16x8*)&area[base +
          ((size_t)((h0 + hl) * 16 + cc) * 32 + (bm & 31)) * 512 + e]);
    }
  }
}

// ---------- proj GEMM: 128x128 tile, same pipeline, out = A*wpt^T + bias ----
__global__ __launch_bounds__(256, 2) void gemm_projT(
    const f16* __restrict__ A,       // prod [G*4096][768] (comp6)
    const f16* __restrict__ Bt,      // wpt [768][768]
    const float* __restrict__ bias, float* __restrict__ Cout) {
  __shared__ f16 lds[32768];
  int id  = blockIdx.x;
  int cpx = gridDim.x >> 3;
  int id2 = (id & 7) * cpx + (id >> 3);       // grid = G*192, %8==0
  int sr = id2 / 48, rr = id2 % 48;
  int bm = sr * 8 + (rr & 7), bn = rr >> 3;   // bm 0..G*32-1, bn 0..5

  int tid = threadIdx.x;
  int wave = tid >> 6, lane = tid & 63;
  int l16 = lane & 15, lq = lane >> 4;
  int wr = wave >> 1, wc = wave & 1;
  int l7 = l16 & 7;
  int cb0 = ((lq) ^ l7) << 4;
  int cb1 = ((4 + lq) ^ l7) << 4;

  const f16* aSrc = A  + (size_t)(bm * 128 + (tid >> 3)) * 768 +
                    (((tid & 7) ^ ((tid >> 3) & 7)) << 3);
  const f16* bSrc = Bt + (size_t)(bn * 128 + (tid >> 3)) * 768 +
                    (((tid & 7) ^ ((tid >> 3) & 7)) << 3);

  f32x4 zz = {0.f, 0.f, 0.f, 0.f};
  f32x4 acc[4][4];
#pragma unroll
  for (int m = 0; m < 4; m++)
#pragma unroll
    for (int n = 0; n < 4; n++) acc[m][n] = zz;

#pragma unroll
  for (int q = 0; q < 4; q++) { QST_A(0, q, 0); }
#pragma unroll
  for (int q = 0; q < 4; q++) { QST_B(0, q, 0); }
#pragma unroll
  for (int q = 0; q < 4; q++) { QST_A(1, q, 1); }
#pragma unroll
  for (int q = 0; q < 4; q++) { QST_B(1, q, 1); }
  asm volatile("s_waitcnt vmcnt(8)" ::: "memory");
  BAR();

  f16x8 af[4][2], bf[4][2];
#pragma unroll 2
  for (int t = 0; t < 12; ++t) {
    int c = t & 1;
    const char* ab = (const char*)lds + c * 32768;
    const char* bb = ab + 16384;
    int rA = wr * 64 + l16;
    int rB = wc * 64 + l16;
#pragma unroll
    for (int mf = 0; mf < 4; mf++) {
      af[mf][0] = *(const f16x8*)(ab + (rA + mf * 16) * 128 + cb0);
      af[mf][1] = *(const f16x8*)(ab + (rA + mf * 16) * 128 + cb1);
    }
#pragma unroll
    for (int nf = 0; nf < 4; nf++) {
      bf[nf][0] = *(const f16x8*)(bb + (rB + nf * 16) * 128 + cb0);
      bf[nf][1] = *(const f16x8*)(bb + (rB + nf * 16) * 128 + cb1);
    }
    asm volatile("s_waitcnt lgkmcnt(0)" ::: "memory");
    BAR();
    if (t < 10) {
#pragma unroll
      for (int q = 0; q < 4; q++) { QST_A(c, q, t + 2); }
#pragma unroll
      for (int q = 0; q < 4; q++) { QST_B(c, q, t + 2); }
    }
    __builtin_amdgcn_s_setprio(1);
#pragma unroll
    for (int ks = 0; ks < 2; ks++)
#pragma unroll
      for (int mf = 0; mf < 4; mf++)
#pragma unroll
        for (int nf = 0; nf < 4; nf++)
          acc[mf][nf] = mm(af[mf][ks], bf[nf][ks], acc[mf][nf]);
    __builtin_amdgcn_s_setprio(0);
    if (t < 10) asm volatile("s_waitcnt vmcnt(8)" ::: "memory");
    else        asm volatile("s_waitcnt vmcnt(0)" ::: "memory");
    BAR();
  }

  // direct fp32 epilogue with bias
#pragma unroll
  for (int ni = 0; ni < 4; ni++) {
    int col = bn * 128 + wc * 64 + ni * 16 + l16;
    float bb = bias[col];
#pragma unroll
    for (int mi = 0; mi < 4; mi++) {
#pragma unroll
      for (int r = 0; r < 4; r++) {
        int row = bm * 128 + wr * 64 + mi * 16 + lq * 4 + r;
        __builtin_nontemporal_store(acc[mi][ni][r] + bb,
                                    &Cout[(size_t)row * 768 + col]);
      }
    }
  }
}

// ---------------- channel attention: per (g,n); xc OUT = [n][h][c][d] -------
__global__ __launch_bounds__(256) void attn_chan_kernel(f16* __restrict__ area,
                                                        long long cstr_) {
  size_t cstr = (size_t)cstr_;
  int blk = blockIdx.x;
  int g = blk >> 8, n = blk & 255;
  size_t goff = (size_t)g * S3;
  int tid = threadIdx.x;
  int wave = tid >> 6, lane = tid & 63;
  int l16 = lane & 15, lq = lane >> 4;
  __shared__ f16 prl[12288];
  __shared__ f16 plds[4][16][40];

  if (lane < 16) {
#pragma unroll
    for (int j = 0; j < 16; j++) plds[wave][lane][16 + j] = (f16)0.f;  // zero K-pad
  }
  __syncthreads();

  f32x4 zz = {0.f, 0.f, 0.f, 0.f};
  for (int hi = 0; hi < 3; hi++) {
    int h = wave + hi * 4;
    const f16* q = area + 0 * cstr + goff + (size_t)((h * 256 + n) * 16) * 64;
    const f16* k = area + 1 * cstr + goff + (size_t)((h * 256 + n) * 16) * 64;
    const f16* v = area + 2 * cstr + goff + (size_t)((h * 256 + n) * 64) * 16; // [d][c]
    f16x8 a0 = *(const f16x8*)&q[l16 * 64 + lq * 8];
    f16x8 a1 = *(const f16x8*)&q[l16 * 64 + 32 + lq * 8];
    f16x8 b0 = *(const f16x8*)&k[l16 * 64 + lq * 8];
    f16x8 b1 = *(const f16x8*)&k[l16 * 64 + 32 + lq * 8];
    f32x4 s = mm(a1, b1, mm(a0, b0, zz));
    float p[4];
#pragma unroll
    for (int r = 0; r < 4; r++) {
      float t = s[r] * 0.125f;
      float mx = t;
      mx = fmaxf(mx, __shfl_xor(mx, 1));
      mx = fmaxf(mx, __shfl_xor(mx, 2));
      mx = fmaxf(mx, __shfl_xor(mx, 4));
      mx = fmaxf(mx, __shfl_xor(mx, 8));
      float e = __expf(t - mx);
      float sum = e;
      sum += __shfl_xor(sum, 1);
      sum += __shfl_xor(sum, 2);
      sum += __shfl_xor(sum, 4);
      sum += __shfl_xor(sum, 8);
      p[r] = e / sum;
    }
#pragma unroll
    for (int r = 0; r < 4; r++)
      plds[wave][lq * 4 + r][l16] = (f16)p[r];
    f16x8 ap = *(const f16x8*)&plds[wave][l16][lq * 8]; // k>=16 are zeros
#pragma unroll
    for (int nt = 0; nt < 4; nt++) {
      f16x8 bv = *(const f16x8*)&v[(nt * 16 + l16) * 16 + lq * 8];
      f32x4 o = mm(ap, bv, zz);
#pragma unroll
      for (int r = 0; r < 4; r++) {
        int cq = lq * 4 + r, d = nt * 16 + l16;
        prl[h * 1024 + cq * 64 + d] = (f16)o[r];
      }
    }
  }
  __syncthreads();
  f16* xc = area + 6 * cstr + goff + (size_t)n * 12288;
#pragma unroll
  for (int i = 0; i < 6; i++) {
    f16x8 v = *(const f16x8*)&prl[i * 2048 + tid * 8];
    __builtin_nontemporal_store(v, (f16x8*)&xc[i * 2048 + tid * 8]);
  }
}

// ---------------- spatial attention + combine: per (g,h,c) ------------------
// Epilogue: prod = O * xc written IN-PLACE over xc (comp6, [n][h][c][d]).
// T13 defer-max on the online softmax.
__global__ __launch_bounds__(512) void attn_spat_kernel(f16* __restrict__ area,
                                                        long long cstr_) {
  size_t cstr = (size_t)cstr_;
  int blk = blockIdx.x;
  int g = blk / 192, rem = blk % 192;
  int h = rem >> 4, c = rem & 15;
  size_t goff = (size_t)g * S3;
  const f16* qs = area + 3 * cstr + goff + (size_t)((h * 16 + c) * 256) * 64;
  const f16* ks = area + 4 * cstr + goff + (size_t)((h * 16 + c) * 256) * 64;
  const f16* vsb = area + 5 * cstr + goff + (size_t)(h * 16 + c) * 16384; // [nb8][d][nl8]
  f16* xcn = area + 6 * cstr + goff;   // xc in / prod out, [n][h][c][d]

  int tid = threadIdx.x;
  int wave = tid >> 6, lane = tid & 63;
  int l16 = lane & 15, lq = lane >> 4;
  __shared__ f16 plds[8][32][40];
  __shared__ f16 osm[16384];          // [256][64] swizzled (oesw)

  f32x4 zz = {0.f, 0.f, 0.f, 0.f};
  f16x8 aq[2][2];
#pragma unroll
  for (int m = 0; m < 2; m++)
#pragma unroll
    for (int kd = 0; kd < 2; kd++)
      aq[m][kd] = *(const f16x8*)&qs[(size_t)(wave * 32 + m * 16 + l16) * 64 + kd * 32 + lq * 8];

  f32x4 o[2][4];
  float mrow[2][4], lrow[2][4];
#pragma unroll
  for (int m = 0; m < 2; m++) {
#pragma unroll
    for (int n = 0; n < 4; n++) o[m][n] = zz;
#pragma unroll
    for (int r = 0; r < 4; r++) { mrow[m][r] = -1e30f; lrow[m][r] = 0.f; }
  }

  for (int kc = 0; kc < 8; kc++) {
    int k0 = kc * 32;
    f16x8 bk00 = *(const f16x8*)&ks[(size_t)(k0 + l16) * 64 + lq * 8];
    f16x8 bk01 = *(const f16x8*)&ks[(size_t)(k0 + l16) * 64 + 32 + lq * 8];
    f16x8 bk10 = *(const f16x8*)&ks[(size_t)(k0 + 16 + l16) * 64 + lq * 8];
    f16x8 bk11 = *(const f16x8*)&ks[(size_t)(k0 + 16 + l16) * 64 + 32 + lq * 8];
    f32x4 st[2][2];
#pragma unroll
    for (int m = 0; m < 2; m++) {
      st[m][0] = mm(aq[m][1], bk01, mm(aq[m][0], bk00, zz));
      st[m][1] = mm(aq[m][1], bk11, mm(aq[m][0], bk10, zz));
    }
#pragma unroll
    for (int m = 0; m < 2; m++) {
#pragma unroll
      for (int r = 0; r < 4; r++) {
        float s0 = st[m][0][r] * 0.125f, s1 = st[m][1][r] * 0.125f;
        float t = fmaxf(s0, s1);
        t = fmaxf(t, __shfl_xor(t, 1));
        t = fmaxf(t, __shfl_xor(t, 2));
        t = fmaxf(t, __shfl_xor(t, 4));
        t = fmaxf(t, __shfl_xor(t, 8));
        float mold = mrow[m][r];
        if (!__all(t - mold <= 8.f)) {   // defer-max
          float mnew = fmaxf(mold, t);
          float fac  = __expf(mold - mnew);
          mrow[m][r] = mnew;
          lrow[m][r] *= fac;
          o[m][0][r] *= fac; o[m][1][r] *= fac; o[m][2][r] *= fac; o[m][3][r] *= fac;
          mold = mnew;
        }
        float p0 = __expf(s0 - mold), p1 = __expf(s1 - mold);
        lrow[m][r] += p0 + p1;
        int prow = m * 16 + lq * 4 + r;
        plds[wave][prow][l16]      = (f16)p0;
        plds[wave][prow][16 + l16] = (f16)p1;
      }
    }
    f16x8 ap0 = *(const f16x8*)&plds[wave][l16][lq * 8];
    f16x8 ap1 = *(const f16x8*)&plds[wave][16 + l16][lq * 8];
#pragma unroll
    for (int n = 0; n < 4; n++) {
      f16x8 bv = *(const f16x8*)&vsb[((k0 >> 3) + lq) * 512 + (n * 16 + l16) * 8];
      o[0][n] = mm(ap0, bv, o[0][n]);
      o[1][n] = mm(ap1, bv, o[1][n]);
    }
  }
#pragma unroll
  for (int m = 0; m < 2; m++)
#pragma unroll
    for (int r = 0; r < 4; r++) {
      float l = lrow[m][r];
      l += __shfl_xor(l, 1);
      l += __shfl_xor(l, 2);
      l += __shfl_xor(l, 4);
      l += __shfl_xor(l, 8);
      lrow[m][r] = 1.0f / l;
    }
#pragma unroll
  for (int m = 0; m < 2; m++)
#pragma unroll
    for (int n = 0; n < 4; n++)
#pragma unroll
      for (int r = 0; r < 4; r++) {
        int row = wave * 32 + m * 16 + lq * 4 + r;
        osm[oesw(row, n * 16 + l16)] = (f16)(o[m][n][r] * lrow[m][r]);
      }
  __syncthreads();
  size_t hc64 = (size_t)(h * 16 + c) * 64;
#pragma unroll
  for (int i = 0; i < 4; i++) {
    int row = i * 64 + (tid >> 3);
    int dp  = (tid & 7) * 8;
    size_t dst = (size_t)row * 12288 + hc64 + dp;
    f16x8 v   = *(const f16x8*)&osm[oesw(row, dp)];
    f16x8 xcv = *(const f16x8*)&xcn[dst];
    f16x8 pv;
#pragma unroll
    for (int j = 0; j < 8; j++)
      pv[j] = (f16)((float)v[j] * (float)xcv[j]);
    __builtin_nontemporal_store(pv, (f16x8*)&xcn[dst]);
  }
}

// ---------------- host ------------------------------------------------------
extern "C" void kernel_launch(void* const* d_in, const int* in_sizes, int n_in,
                              void* d_out, int out_size, void* d_ws, size_t ws_size,
                              hipStream_t stream) {
  const float* x      = (const float*)d_in[0];
  const float* w_qkv  = (const float*)d_in[1];
  const float* w_proj = (const float*)d_in[2];
  const float* b_proj = (const float*)d_in[3];
  float* out = (float*)d_out;
  f16* ws = (f16*)d_ws;

  const size_t W16T = 4608ull * 768;
  const size_t WPT  = 768ull * 768;
  f16* w16t = ws;
  f16* wpt  = ws + W16T;
  f16* area = wpt + WPT;

  // 7-component plan: 0 qc, 1 kc, 2 vc, 3 qs, 4 ks, 5 vs, 6 x16->xc->prod
  int G = 8;  // batches per chunk; shrink until scratch fits
  while (G > 1 && (W16T + WPT + 7ull * G * S3) * 2 > ws_size) G >>= 1;
  int nch = 8 / G;
  long long cstr = (long long)G * S3;
  f16* x16 = area + 6 * (size_t)cstr;

  cvt_T_kernel<<<dim3(144, 24), 256, 0, stream>>>(w_qkv, w16t, 768, 4608);
  cvt_T_kernel<<<dim3(24, 24), 256, 0, stream>>>(w_proj, wpt, 768, 768);

  for (int ch = 0; ch < nch; ch++) {
    size_t b0 = (size_t)ch * G;
    cvt_x_kernel<<<G * 1536, 256, 0, stream>>>(x + b0 * S3, x16);
    gemm_qkvT<<<G * 1152, 256, 0, stream>>>(x16, w16t, area, cstr);
    attn_chan_kernel<<<G * 256, 256, 0, stream>>>(area, cstr);   // xc -> comp6
    attn_spat_kernel<<<G * 192, 512, 0, stream>>>(area, cstr);   // prod in-place
    gemm_projT<<<G * 192, 256, 0, stream>>>(area + 6 * (size_t)cstr, wpt, b_proj,
                                            out + b0 * S3);
  }
}